// Round 6
// baseline (167.534 us; speedup 1.0000x reference)
//
#include <hip/hip_runtime.h>

typedef __bf16 bf16_t;
typedef __bf16 bf16x4_t __attribute__((ext_vector_type(4)));
typedef __bf16 bf16x8 __attribute__((ext_vector_type(8)));
typedef float f32x4 __attribute__((ext_vector_type(4)));

#define NH 8
#define DH 32
#define QL 256
#define KL 256
#define CIN 64
#define HD 256  // NH*DH

__device__ __forceinline__ bf16_t f2bf(float x) { return (bf16_t)x; }

__device__ __forceinline__ f32x4 mfma16(bf16x8 a, bf16x8 b, f32x4 c) {
    return __builtin_amdgcn_mfma_f32_16x16x32_bf16(a, b, c, 0, 0, 0);
}

// ---------------------------------------------------------------------------
// pack_w: one-time repack of Wq/Wk/Wv/Wo into fragment-native bf16 layout.
// Frag elem j at lane(quad,l16):
//   WqF/WkF/WvF: W[ks*32+quad*8+j][h*32 + nt*16 + l16]   (B-operand, proj)
//   WoF:         Wo[h*32+quad*8+j][nt*16 + l16]          (B-operand, outproj)
__launch_bounds__(256)
__global__ void pack_w(const float* __restrict__ Wq, const float* __restrict__ Wk,
                       const float* __restrict__ Wv, const float* __restrict__ Wo,
                       bf16_t* __restrict__ WqF, bf16_t* __restrict__ WkF,
                       bf16_t* __restrict__ WvF, bf16_t* __restrict__ WoF) {
    const int h = blockIdx.x;
    const int tid = threadIdx.x, lane = tid & 63, w = tid >> 6;
    const int quad = lane >> 4, l16 = lane & 15;
    if (w < 3) {
        const float* __restrict__ W = (w == 0) ? Wq : (w == 1 ? Wk : Wv);
        bf16_t* __restrict__ F = (w == 0) ? WqF : (w == 1 ? WkF : WvF);
#pragma unroll
        for (int nt = 0; nt < 2; ++nt)
#pragma unroll
            for (int ks = 0; ks < 2; ++ks) {
                bf16x8 f;
#pragma unroll
                for (int j = 0; j < 8; ++j)
                    f[j] = f2bf(W[(ks * 32 + quad * 8 + j) * HD + h * DH + nt * 16 + l16]);
                *(bf16x8*)&F[(size_t)((h * 4 + nt * 2 + ks) * 512) + lane * 8] = f;
            }
    } else {
#pragma unroll
        for (int nt = 0; nt < 4; ++nt) {
            bf16x8 f;
#pragma unroll
            for (int j = 0; j < 8; ++j)
                f[j] = f2bf(Wo[(h * DH + quad * 8 + j) * CIN + nt * 16 + l16]);
            *(bf16x8*)&WoF[(size_t)((h * 4 + nt) * 512) + lane * 8] = f;
        }
    }
}

// ---------------------------------------------------------------------------
// fused_pipe2: r5's 1-barrier head pipeline + r6 stall fixes:
//  (1) K-proj operand-SWAPPED: mfma(bw_asA, xk_asB) = (X·Wk)^T -> lane holds
//      4 consecutive d at fixed kv -> 8 b64 stores (was 32 b16 @4-way) into
//      the r4-proven XOR-swizzled sK[256][32]; both sides at bank floor.
//  (2) sVT -> swizzled [32][256] (chunk ^= d&7); sPT stride-72 swizzled
//      (chunk ^= qrow&7): all repack writes/reads at b64/b128 floor
//      (r5: every such path was a structural 4-way conflict, 5.37M cyc).
//  (3) bias(h+1) prefetched into regs mid-phase h, consumed as QK's
//      C-operand; Q-proj(h+1) hoisted to phase h end -> QK(h) issues at
//      phase start with zero latency in front.
//  (4) s_setprio(1) around QK/PV MFMA clusters.
__launch_bounds__(256, 2)
__global__ void fused_pipe2(const float* __restrict__ Xq, const float* __restrict__ Xkv,
                            const float* __restrict__ Mask, const float* __restrict__ Bias,
                            const bf16_t* __restrict__ WqF, const bf16_t* __restrict__ WkF,
                            const bf16_t* __restrict__ WvF, const bf16_t* __restrict__ WoF,
                            const float* __restrict__ Bo, float* __restrict__ Out) {
    const int b = blockIdx.x;
    const int s = b & 127, qq = b >> 7;   // s fastest: same-s blocks share an XCD
    const int tid = threadIdx.x, lane = tid & 63, w = tid >> 6;
    const int quad = lane >> 4, l16 = lane & 15;
    const int tg = qq * 4 + w;            // this wave's global q-tile (16 rows)
    const f32x4 vzero = {0.f, 0.f, 0.f, 0.f};

    __shared__ __attribute__((aligned(16))) bf16_t sK[2][KL * 32];   // 32 KB dbuf, swz
    __shared__ __attribute__((aligned(16))) bf16_t sVT[2][DH * 256]; // 32 KB dbuf, swz
    __shared__ __attribute__((aligned(16))) bf16_t sPT[4][16 * 72];  //  9 KB bounce, swz
    __shared__ __attribute__((aligned(16))) float sMask[KL];         //  1 KB

    if (tid < 64) {
        const f32x4 m4 = *(const f32x4*)&Mask[s * KL + tid * 4];
        f32x4 mm;
#pragma unroll
        for (int j = 0; j < 4; ++j) mm[j] = (m4[j] - 1.0f) * 1.0e9f;
        *(f32x4*)&sMask[tid * 4] = mm;
    }

    // ---- X fragments, register-resident for all 8 heads ----
    bf16x8 xk[4][2];  // Xkv A/B-frags: wave owns kv-tiles {4w..4w+3}
#pragma unroll
    for (int t = 0; t < 4; ++t) {
        const int row = (w * 4 + t) * 16 + l16;
        const float* src = &Xkv[(size_t)(s * QL + row) * CIN];
#pragma unroll
        for (int ks = 0; ks < 2; ++ks) {
            const f32x4 lo = *(const f32x4*)&src[ks * 32 + quad * 8];
            const f32x4 hi = *(const f32x4*)&src[ks * 32 + quad * 8 + 4];
            bf16x8 f;
#pragma unroll
            for (int j = 0; j < 4; ++j) { f[j] = f2bf(lo[j]); f[4 + j] = f2bf(hi[j]); }
            xk[t][ks] = f;
        }
    }
    bf16x8 xq[2];  // Xq A-frags for this wave's q-tile, pre-scaled 1/sqrt(32)
    {
        const int row = tg * 16 + l16;
        const float* src = &Xq[(size_t)(s * QL + row) * CIN];
#pragma unroll
        for (int ks = 0; ks < 2; ++ks) {
            const f32x4 lo = *(const f32x4*)&src[ks * 32 + quad * 8];
            const f32x4 hi = *(const f32x4*)&src[ks * 32 + quad * 8 + 4];
            bf16x8 f;
#pragma unroll
            for (int j = 0; j < 4; ++j) {
                f[j] = f2bf(lo[j] * 0.17677669529663687f);
                f[4 + j] = f2bf(hi[j] * 0.17677669529663687f);
            }
            xq[ks] = f;
        }
    }

    // K^T/V projection of head h into LDS buffer buf (all stores at bank floor)
    auto projKV = [&](int h, int buf) {
        bf16x8 bk[2][2], bv[2][2];
#pragma unroll
        for (int nt = 0; nt < 2; ++nt)
#pragma unroll
            for (int ks = 0; ks < 2; ++ks) {
                bk[nt][ks] = *(const bf16x8*)&WkF[(size_t)((h * 4 + nt * 2 + ks) * 512) + lane * 8];
                bv[nt][ks] = *(const bf16x8*)&WvF[(size_t)((h * 4 + nt * 2 + ks) * 512) + lane * 8];
            }
        // K^T = Wk^T·Xkv^T via operand swap: lane holds K^T[d=nt*16+quad*4+r][kv]
        // -> b64 of 4 consecutive d at sK[kv][d], chunk ^= (kv>>2)&3
        const int rsw = (l16 >> 2) & 3;
#pragma unroll
        for (int t = 0; t < 4; ++t) {
            const int kv = (w * 4 + t) * 16 + l16;
#pragma unroll
            for (int nt = 0; nt < 2; ++nt) {
                f32x4 c = mfma16(bk[nt][0], xk[t][0], vzero);
                c = mfma16(bk[nt][1], xk[t][1], c);
                bf16x4_t p;
#pragma unroll
                for (int r = 0; r < 4; ++r) p[r] = f2bf(c[r]);
                const int ch = (nt * 2 + (quad >> 1)) ^ rsw;
                *(bf16x4_t*)&sK[buf][kv * 32 + ch * 8 + (quad & 1) * 4] = p;
            }
        }
        // V (normal orientation): lane holds V[kv=16T+quad*4+r][d=nt*16+l16]
        // -> b64 of 4 consecutive kv at sVT[d][kv], chunk ^= d&7
#pragma unroll
        for (int t = 0; t < 4; ++t) {
            const int ch0 = (w * 4 + t) * 2 + (quad >> 1);  // kv0>>3
#pragma unroll
            for (int nt = 0; nt < 2; ++nt) {
                f32x4 c = mfma16(xk[t][0], bv[nt][0], vzero);
                c = mfma16(xk[t][1], bv[nt][1], c);
                bf16x4_t p;
#pragma unroll
                for (int r = 0; r < 4; ++r) p[r] = f2bf(c[r]);
                const int d = nt * 16 + l16;
                const int ch = ch0 ^ (l16 & 7);
                *(bf16x4_t*)&sVT[buf][d * 256 + ch * 8 + (quad & 1) * 4] = p;
            }
        }
    };

    // Q projection (per-wave sPT bounce, same-wave DS order; swizzled)
    auto projQ = [&](int h) -> bf16x8 {
        bf16x8 bq[2][2];
#pragma unroll
        for (int nt = 0; nt < 2; ++nt)
#pragma unroll
            for (int ks = 0; ks < 2; ++ks)
                bq[nt][ks] = *(const bf16x8*)&WqF[(size_t)((h * 4 + nt * 2 + ks) * 512) + lane * 8];
#pragma unroll
        for (int nt = 0; nt < 2; ++nt) {
            f32x4 c = mfma16(xq[0], bq[nt][0], vzero);
            c = mfma16(xq[1], bq[nt][1], c);
#pragma unroll
            for (int r = 0; r < 4; ++r) {
                const int row = quad * 4 + r;
                const int col = nt * 16 + l16;
                const int ch = (col >> 3) ^ (row & 7);
                sPT[w][row * 72 + ch * 8 + (col & 7)] = f2bf(c[r]);
            }
        }
        return *(const bf16x8*)&sPT[w][l16 * 72 + (quad ^ (l16 & 7)) * 8];
    };

    f32x4 acc[4];  // output accumulator: 16 q-rows x 64 out-cols
#pragma unroll
    for (int nt = 0; nt < 4; ++nt) acc[nt] = vzero;

    // ---- prologue: bias(0) in flight, K/V(0) -> buf0, qfr(0) ready ----
    f32x4 bias[16];
    {
        const float* bb = &Bias[(size_t)(tg * 16 + l16) * KL];
#pragma unroll
        for (int ct = 0; ct < 16; ++ct) bias[ct] = *(const f32x4*)&bb[ct * 16 + quad * 4];
    }
    projKV(0, 0);
    bf16x8 qfr = projQ(0);
    __syncthreads();  // buf0 + sMask visible

#pragma unroll 1
    for (int h = 0; h < NH; ++h) {
        const int p = h & 1;

        // ---- QK immediately: qfr + bias both ready from last phase ----
        f32x4 sv[16];
        __builtin_amdgcn_s_setprio(1);
#pragma unroll
        for (int ct = 0; ct < 16; ++ct) {
            const int row = ct * 16 + l16;
            const int ch = quad ^ ((l16 >> 2) & 3);
            const bf16x8 ak = *(const bf16x8*)&sK[p][row * 32 + ch * 8];
            sv[ct] = mfma16(ak, qfr, bias[ct]);  // C = bias (mask added below)
        }
        __builtin_amdgcn_s_setprio(0);

        // ---- bias(h+1) prefetch (global latency hides under rest of phase) ----
        if (h + 1 < NH) {
            const float* bb = &Bias[(size_t)((h + 1) * QL + tg * 16 + l16) * KL];
#pragma unroll
            for (int ct = 0; ct < 16; ++ct) bias[ct] = *(const f32x4*)&bb[ct * 16 + quad * 4];
        }

        // ---- proj(h+1) into buf 1-p: independent MFMA filler ----
        if (h + 1 < NH) projKV(h + 1, p ^ 1);

        // ---- Wo frags (global, L2-hot; used at phase end) ----
        bf16x8 bwo[4];
#pragma unroll
        for (int nt = 0; nt < 4; ++nt)
            bwo[nt] = *(const bf16x8*)&WoF[(size_t)((h * 4 + nt) * 512) + lane * 8];

        // ---- mask add + softmax (tree-reduced) ----
#pragma unroll
        for (int ct = 0; ct < 16; ++ct)
            sv[ct] += *(const f32x4*)&sMask[ct * 16 + quad * 4];  // broadcast read
        f32x4 vmx = sv[0];
#pragma unroll
        for (int ct = 1; ct < 16; ++ct)
#pragma unroll
            for (int r = 0; r < 4; ++r) vmx[r] = fmaxf(vmx[r], sv[ct][r]);
        float mx = fmaxf(fmaxf(vmx[0], vmx[1]), fmaxf(vmx[2], vmx[3]));
        mx = fmaxf(mx, __shfl_xor(mx, 16, 64));
        mx = fmaxf(mx, __shfl_xor(mx, 32, 64));
        f32x4 vsum = vzero;
#pragma unroll
        for (int ct = 0; ct < 16; ++ct)
#pragma unroll
            for (int r = 0; r < 4; ++r) {
                const float e = __expf(sv[ct][r] - mx);
                sv[ct][r] = e;
                vsum[r] += e;
            }
        float sum = (vsum[0] + vsum[1]) + (vsum[2] + vsum[3]);
        sum += __shfl_xor(sum, 16, 64);
        sum += __shfl_xor(sum, 32, 64);
        const float rs = 1.0f / sum;

        // ---- PV in four 64-kv chunks: P^T -> sPT (swz) -> A-frags; V from sVT[p] ----
        f32x4 o0 = vzero, o1 = vzero;
#pragma unroll
        for (int c = 0; c < 4; ++c) {
#pragma unroll
            for (int cc = 0; cc < 4; ++cc) {
                const int ct = c * 4 + cc;
                bf16x4_t pv;
#pragma unroll
                for (int r = 0; r < 4; ++r) pv[r] = f2bf(sv[ct][r] * rs);
                const int ch = (cc * 2 + (quad >> 1)) ^ (l16 & 7);
                *(bf16x4_t*)&sPT[w][l16 * 72 + ch * 8 + (quad & 1) * 4] = pv;
            }
            __builtin_amdgcn_s_setprio(1);
#pragma unroll
            for (int ks = 0; ks < 2; ++ks) {
                const int ch = (ks * 4 + quad) ^ (l16 & 7);
                const bf16x8 ap = *(const bf16x8*)&sPT[w][l16 * 72 + ch * 8];
                const int cs = c * 2 + ks;
                const int chv = (cs * 4 + quad) ^ (l16 & 7);
                const bf16x8 v0 = *(const bf16x8*)&sVT[p][l16 * 256 + chv * 8];
                const bf16x8 v1 = *(const bf16x8*)&sVT[p][(16 + l16) * 256 + chv * 8];
                o0 = mfma16(ap, v0, o0);
                o1 = mfma16(ap, v1, o1);
            }
            __builtin_amdgcn_s_setprio(0);
        }

        // ---- outproj accumulate via sPT bounce (same-wave DS order) ----
        {
#pragma unroll
            for (int r = 0; r < 4; ++r) {
                const int row = quad * 4 + r;
                const int ch0 = (l16 >> 3) ^ (row & 7);
                const int ch1 = (2 + (l16 >> 3)) ^ (row & 7);
                sPT[w][row * 72 + ch0 * 8 + (l16 & 7)] = f2bf(o0[r]);
                sPT[w][row * 72 + ch1 * 8 + (l16 & 7)] = f2bf(o1[r]);
            }
            const bf16x8 af = *(const bf16x8*)&sPT[w][l16 * 72 + (quad ^ (l16 & 7)) * 8];
#pragma unroll
            for (int nt = 0; nt < 4; ++nt) acc[nt] = mfma16(af, bwo[nt], acc[nt]);
        }

        // ---- Q-proj(h+1): qfr ready before next phase's QK ----
        if (h + 1 < NH) qfr = projQ(h + 1);

        __syncthreads();  // single barrier/head: buf 1-p ready, buf p free
    }

    // -------------------- epilogue: direct store --------------------
    const int orow = s * QL + tg * 16 + quad * 4;
#pragma unroll
    for (int nt = 0; nt < 4; ++nt) {
        const float bo = Bo[nt * 16 + l16];
#pragma unroll
        for (int r = 0; r < 4; ++r)
            Out[(size_t)(orow + r) * CIN + nt * 16 + l16] = acc[nt][r] + bo;
    }
}

extern "C" void kernel_launch(void* const* d_in, const int* in_sizes, int n_in,
                              void* d_out, int out_size, void* d_ws, size_t ws_size,
                              hipStream_t stream) {
    const float* Xq   = (const float*)d_in[0];
    const float* Xkv  = (const float*)d_in[1];
    const float* Mask = (const float*)d_in[2];
    const float* Bias = (const float*)d_in[3];
    const float* Wq   = (const float*)d_in[4];
    const float* Wk   = (const float*)d_in[5];
    const float* Wv   = (const float*)d_in[6];
    const float* Wo   = (const float*)d_in[7];
    const float* Bo   = (const float*)d_in[8];
    float* Out = (float*)d_out;

    // 128 KB of fragment-native weights at the head of ws
    bf16_t* WqF = (bf16_t*)d_ws;
    bf16_t* WkF = WqF + 16384;
    bf16_t* WvF = WkF + 16384;
    bf16_t* WoF = WvF + 16384;

    pack_w<<<dim3(NH), 256, 0, stream>>>(Wq, Wk, Wv, Wo, WqF, WkF, WvF, WoF);
    fused_pipe2<<<dim3(512), 256, 0, stream>>>(Xq, Xkv, Mask, Bias,
                                               WqF, WkF, WvF, WoF, Bo, Out);
}

// Round 7
// 158.863 us; speedup vs baseline: 1.0546x; 1.0546x over previous
//
#include <hip/hip_runtime.h>

typedef __bf16 bf16_t;
typedef __bf16 bf16x4_t __attribute__((ext_vector_type(4)));
typedef __bf16 bf16x8 __attribute__((ext_vector_type(8)));
typedef float f32x4 __attribute__((ext_vector_type(4)));

#define NH 8
#define DH 32
#define QL 256
#define KL 256
#define CIN 64
#define HD 256  // NH*DH

__device__ __forceinline__ bf16_t f2bf(float x) { return (bf16_t)x; }

__device__ __forceinline__ f32x4 mfma16(bf16x8 a, bf16x8 b, f32x4 c) {
    return __builtin_amdgcn_mfma_f32_16x16x32_bf16(a, b, c, 0, 0, 0);
}

// ---------------------------------------------------------------------------
// pack_w: one-time repack of Wq/Wk/Wv/Wo into fragment-native bf16 layout.
// Frag elem j at lane(quad,l16):
//   WqF/WkF/WvF: W[ks*32+quad*8+j][h*32 + nt*16 + l16]   (B-operand, proj)
//   WoF:         Wo[h*32+quad*8+j][nt*16 + l16]          (B-operand, outproj)
__launch_bounds__(256)
__global__ void pack_w(const float* __restrict__ Wq, const float* __restrict__ Wk,
                       const float* __restrict__ Wv, const float* __restrict__ Wo,
                       bf16_t* __restrict__ WqF, bf16_t* __restrict__ WkF,
                       bf16_t* __restrict__ WvF, bf16_t* __restrict__ WoF) {
    const int h = blockIdx.x;
    const int tid = threadIdx.x, lane = tid & 63, w = tid >> 6;
    const int quad = lane >> 4, l16 = lane & 15;
    if (w < 3) {
        const float* __restrict__ W = (w == 0) ? Wq : (w == 1 ? Wk : Wv);
        bf16_t* __restrict__ F = (w == 0) ? WqF : (w == 1 ? WkF : WvF);
#pragma unroll
        for (int nt = 0; nt < 2; ++nt)
#pragma unroll
            for (int ks = 0; ks < 2; ++ks) {
                bf16x8 f;
#pragma unroll
                for (int j = 0; j < 8; ++j)
                    f[j] = f2bf(W[(ks * 32 + quad * 8 + j) * HD + h * DH + nt * 16 + l16]);
                *(bf16x8*)&F[(size_t)((h * 4 + nt * 2 + ks) * 512) + lane * 8] = f;
            }
    } else {
#pragma unroll
        for (int nt = 0; nt < 4; ++nt) {
            bf16x8 f;
#pragma unroll
            for (int j = 0; j < 8; ++j)
                f[j] = f2bf(Wo[(h * DH + quad * 8 + j) * CIN + nt * 16 + l16]);
            *(bf16x8*)&WoF[(size_t)((h * 4 + nt) * 512) + lane * 8] = f;
        }
    }
}

// ---------------------------------------------------------------------------
// fused_sb: one block = (s, q-quarter, 4-head group); 1024 blocks.
// r7 = r5's pipeline with the TLP package:
//  - SINGLE-buffered sK/sVT (QK at phase start; K(h+1) overwrites sK after
//    barrier 1, V(h+1) after barrier 2) -> LDS 43.5 KB -> 3 blocks/CU.
//  - head-split grid (1024 blocks) so the 3rd residency slot is fillable;
//    s stays fastest (r4: reordering destroyed Xkv/Out L2 locality).
//  - bias(h+1) prefetched into sv at phase TAIL (sv dead after PV; zero
//    extra registers -- r6's bias[16] array spilled, withdrawn).
//  - all LDS index math r5-verbatim (r6's "improved" swizzles DOUBLED
//    conflicts on HW; reverted).
//  - atomic f32 epilogue over memset base (r2-proven).
__launch_bounds__(256, 3)
__global__ void fused_sb(const float* __restrict__ Xq, const float* __restrict__ Xkv,
                         const float* __restrict__ Mask, const float* __restrict__ Bias,
                         const bf16_t* __restrict__ WqF, const bf16_t* __restrict__ WkF,
                         const bf16_t* __restrict__ WvF, const bf16_t* __restrict__ WoF,
                         const float* __restrict__ Bo, float* __restrict__ Out) {
    const int b = blockIdx.x;
    const int s = b & 127;                 // s fastest: XCD = s&7 (Xkv/Out locality)
    const int qq = (b >> 7) & 3, hg = b >> 9;
    const int tid = threadIdx.x, lane = tid & 63, w = tid >> 6;
    const int quad = lane >> 4, l16 = lane & 15;
    const int tg = qq * 4 + w;             // this wave's global q-tile (16 rows)
    const f32x4 vzero = {0.f, 0.f, 0.f, 0.f};

    __shared__ __attribute__((aligned(16))) bf16_t sK[KL * 32];     // 16.0 KB swz (r4/r5)
    __shared__ __attribute__((aligned(16))) bf16_t sVT[DH][264];    // 16.5 KB (r5)
    __shared__ __attribute__((aligned(16))) bf16_t sPT[4][16][72];  //  9.0 KB bounce (r5)
    __shared__ __attribute__((aligned(16))) float sMask[KL];        //  1.0 KB

    if (tid < 64) {
        const f32x4 m4 = *(const f32x4*)&Mask[s * KL + tid * 4];
        f32x4 mm;
#pragma unroll
        for (int j = 0; j < 4; ++j) mm[j] = (m4[j] - 1.0f) * 1.0e9f;
        *(f32x4*)&sMask[tid * 4] = mm;
    }

    // ---- X fragments, register-resident for all 4 heads of this group ----
    bf16x8 xk[4][2];  // Xkv A-frags: wave owns kv-tiles {4w..4w+3}
#pragma unroll
    for (int t = 0; t < 4; ++t) {
        const int row = (w * 4 + t) * 16 + l16;
        const float* src = &Xkv[(size_t)(s * QL + row) * CIN];
#pragma unroll
        for (int ks = 0; ks < 2; ++ks) {
            const f32x4 lo = *(const f32x4*)&src[ks * 32 + quad * 8];
            const f32x4 hi = *(const f32x4*)&src[ks * 32 + quad * 8 + 4];
            bf16x8 f;
#pragma unroll
            for (int j = 0; j < 4; ++j) { f[j] = f2bf(lo[j]); f[4 + j] = f2bf(hi[j]); }
            xk[t][ks] = f;
        }
    }
    bf16x8 xq[2];  // Xq A-frags for this wave's q-tile, pre-scaled 1/sqrt(32)
    {
        const int row = tg * 16 + l16;
        const float* src = &Xq[(size_t)(s * QL + row) * CIN];
#pragma unroll
        for (int ks = 0; ks < 2; ++ks) {
            const f32x4 lo = *(const f32x4*)&src[ks * 32 + quad * 8];
            const f32x4 hi = *(const f32x4*)&src[ks * 32 + quad * 8 + 4];
            bf16x8 f;
#pragma unroll
            for (int j = 0; j < 4; ++j) {
                f[j] = f2bf(lo[j] * 0.17677669529663687f);
                f[4 + j] = f2bf(hi[j] * 0.17677669529663687f);
            }
            xq[ks] = f;
        }
    }

    // K projection of head h -> swizzled sK (r4/r5-proven indexing)
    auto projK = [&](int h) {
        bf16x8 bk[2][2];
#pragma unroll
        for (int nt = 0; nt < 2; ++nt)
#pragma unroll
            for (int ks = 0; ks < 2; ++ks)
                bk[nt][ks] = *(const bf16x8*)&WkF[(size_t)((h * 4 + nt * 2 + ks) * 512) + lane * 8];
#pragma unroll
        for (int t = 0; t < 4; ++t) {
            const int r0 = (w * 4 + t) * 16 + quad * 4;
#pragma unroll
            for (int nt = 0; nt < 2; ++nt) {
                f32x4 c = mfma16(xk[t][0], bk[nt][0], vzero);
                c = mfma16(xk[t][1], bk[nt][1], c);
                const int chS = ((nt * 2 + (l16 >> 3)) ^ quad) << 3;
#pragma unroll
                for (int r = 0; r < 4; ++r)
                    sK[(r0 + r) * 32 + chS + (l16 & 7)] = f2bf(c[r]);
            }
        }
    };
    // V projection of head h -> sVT transpose-store (r5-proven indexing)
    auto projV = [&](int h) {
        bf16x8 bv[2][2];
#pragma unroll
        for (int nt = 0; nt < 2; ++nt)
#pragma unroll
            for (int ks = 0; ks < 2; ++ks)
                bv[nt][ks] = *(const bf16x8*)&WvF[(size_t)((h * 4 + nt * 2 + ks) * 512) + lane * 8];
#pragma unroll
        for (int t = 0; t < 4; ++t) {
            const int c0 = (w * 4 + t) * 16 + quad * 4;
#pragma unroll
            for (int nt = 0; nt < 2; ++nt) {
                f32x4 c = mfma16(xk[t][0], bv[nt][0], vzero);
                c = mfma16(xk[t][1], bv[nt][1], c);
                bf16x4_t p4;
#pragma unroll
                for (int r = 0; r < 4; ++r) p4[r] = f2bf(c[r]);
                *(bf16x4_t*)&sVT[nt * 16 + l16][c0] = p4;
            }
        }
    };
    // Q projection (per-wave sPT bounce, same-wave DS order; r5-proven)
    auto projQ = [&](int h) -> bf16x8 {
        bf16x8 bq[2][2];
#pragma unroll
        for (int nt = 0; nt < 2; ++nt)
#pragma unroll
            for (int ks = 0; ks < 2; ++ks)
                bq[nt][ks] = *(const bf16x8*)&WqF[(size_t)((h * 4 + nt * 2 + ks) * 512) + lane * 8];
#pragma unroll
        for (int nt = 0; nt < 2; ++nt) {
            f32x4 c = mfma16(xq[0], bq[nt][0], vzero);
            c = mfma16(xq[1], bq[nt][1], c);
#pragma unroll
            for (int r = 0; r < 4; ++r) sPT[w][quad * 4 + r][nt * 16 + l16] = f2bf(c[r]);
        }
        return *(const bf16x8*)&sPT[w][l16][quad * 8];
    };

    f32x4 acc[4];  // output accumulator: 16 q-rows x 64 out-cols (this head group)
#pragma unroll
    for (int nt = 0; nt < 4; ++nt) acc[nt] = vzero;

    // ---- prologue: bias(h0) -> sv (in flight), K/V/Q(h0) ----
    f32x4 sv[16];
    {
        const float* bb = &Bias[(size_t)(hg * 4 * QL + tg * 16 + l16) * KL];
#pragma unroll
        for (int ct = 0; ct < 16; ++ct) sv[ct] = *(const f32x4*)&bb[ct * 16 + quad * 4];
    }
    projK(hg * 4);
    projV(hg * 4);
    bf16x8 qfr = projQ(hg * 4);
    __syncthreads();  // sK/sVT/sMask visible

#pragma unroll 1
    for (int hh = 0; hh < 4; ++hh) {
        const int h = hg * 4 + hh;

        // ---- QK at phase start: qfr + sv(=bias) ready from previous tail ----
#pragma unroll
        for (int ct = 0; ct < 16; ++ct) {
            const int row = ct * 16 + l16;
            const int chS = (quad ^ ((l16 >> 2) & 3)) << 3;
            const bf16x8 ak = *(const bf16x8*)&sK[row * 32 + chS];
            sv[ct] = mfma16(ak, qfr, sv[ct]);  // bias rides C; mask added below
        }

        __syncthreads();  // B1: all waves done reading sK

        // ---- K-proj(h+1) overwrites sK: independent MFMA filler for softmax ----
        if (hh < 3) projK(h + 1);

        // ---- mask add + softmax (tree-reduced) ----
#pragma unroll
        for (int ct = 0; ct < 16; ++ct)
            sv[ct] += *(const f32x4*)&sMask[ct * 16 + quad * 4];  // broadcast read
        f32x4 vmx = sv[0];
#pragma unroll
        for (int ct = 1; ct < 16; ++ct)
#pragma unroll
            for (int r = 0; r < 4; ++r) vmx[r] = fmaxf(vmx[r], sv[ct][r]);
        float mx = fmaxf(fmaxf(vmx[0], vmx[1]), fmaxf(vmx[2], vmx[3]));
        mx = fmaxf(mx, __shfl_xor(mx, 16, 64));
        mx = fmaxf(mx, __shfl_xor(mx, 32, 64));
        f32x4 vsum = vzero;
#pragma unroll
        for (int ct = 0; ct < 16; ++ct)
#pragma unroll
            for (int r = 0; r < 4; ++r) {
                const float e = __expf(sv[ct][r] - mx);
                sv[ct][r] = e;
                vsum[r] += e;
            }
        float sum = (vsum[0] + vsum[1]) + (vsum[2] + vsum[3]);
        sum += __shfl_xor(sum, 16, 64);
        sum += __shfl_xor(sum, 32, 64);
        const float rs = 1.0f / sum;

        // ---- PV in four 64-kv chunks: P^T -> sPT -> A-frags; V from sVT ----
        f32x4 o0 = vzero, o1 = vzero;
#pragma unroll
        for (int c = 0; c < 4; ++c) {
#pragma unroll
            for (int cc = 0; cc < 4; ++cc) {
                const int ct = c * 4 + cc;
                bf16x4_t pv;
#pragma unroll
                for (int r = 0; r < 4; ++r) pv[r] = f2bf(sv[ct][r] * rs);
                *(bf16x4_t*)&sPT[w][l16][cc * 16 + quad * 4] = pv;
            }
#pragma unroll
            for (int ks = 0; ks < 2; ++ks) {
                const bf16x8 ap = *(const bf16x8*)&sPT[w][l16][ks * 32 + quad * 8];
                const int cs = c * 2 + ks;
                const bf16x8 v0 = *(const bf16x8*)&sVT[l16][cs * 32 + quad * 8];
                const bf16x8 v1 = *(const bf16x8*)&sVT[16 + l16][cs * 32 + quad * 8];
                o0 = mfma16(ap, v0, o0);
                o1 = mfma16(ap, v1, o1);
            }
        }

        __syncthreads();  // B2: sVT free (PV done); sK(h+1) visible for next QK

        // ---- V-proj(h+1) overwrites sVT (ready by next phase's B1) ----
        if (hh < 3) projV(h + 1);

        // ---- outproj accumulate via per-wave sPT bounce ----
        {
            bf16x8 bwo[4];
#pragma unroll
            for (int nt = 0; nt < 4; ++nt)
                bwo[nt] = *(const bf16x8*)&WoF[(size_t)((h * 4 + nt) * 512) + lane * 8];
#pragma unroll
            for (int r = 0; r < 4; ++r) {
                sPT[w][quad * 4 + r][l16] = f2bf(o0[r]);
                sPT[w][quad * 4 + r][16 + l16] = f2bf(o1[r]);
            }
            const bf16x8 af = *(const bf16x8*)&sPT[w][l16][quad * 8];
#pragma unroll
            for (int nt = 0; nt < 4; ++nt) acc[nt] = mfma16(af, bwo[nt], acc[nt]);
        }

        // ---- tail: Q(h+1) + bias(h+1) into sv (dead after PV; zero extra regs) ----
        if (hh < 3) {
            qfr = projQ(h + 1);
            const float* bb = &Bias[(size_t)((h + 1) * QL + tg * 16 + l16) * KL];
#pragma unroll
            for (int ct = 0; ct < 16; ++ct) sv[ct] = *(const f32x4*)&bb[ct * 16 + quad * 4];
        }
        // no barrier here: next QK reads sK (covered by B2); next PV reads
        // sVT written above (covered by next phase's B1).
    }

    // ---- epilogue: combine head-group partials via f32 atomics ----
    const int orow = s * QL + tg * 16 + quad * 4;
#pragma unroll
    for (int nt = 0; nt < 4; ++nt) {
        const float bo = (hg == 0) ? Bo[nt * 16 + l16] : 0.0f;
#pragma unroll
        for (int r = 0; r < 4; ++r)
            atomicAdd(&Out[(size_t)(orow + r) * CIN + nt * 16 + l16], acc[nt][r] + bo);
    }
}

extern "C" void kernel_launch(void* const* d_in, const int* in_sizes, int n_in,
                              void* d_out, int out_size, void* d_ws, size_t ws_size,
                              hipStream_t stream) {
    const float* Xq   = (const float*)d_in[0];
    const float* Xkv  = (const float*)d_in[1];
    const float* Mask = (const float*)d_in[2];
    const float* Bias = (const float*)d_in[3];
    const float* Wq   = (const float*)d_in[4];
    const float* Wk   = (const float*)d_in[5];
    const float* Wv   = (const float*)d_in[6];
    const float* Wo   = (const float*)d_in[7];
    const float* Bo   = (const float*)d_in[8];
    float* Out = (float*)d_out;

    // 128 KB of fragment-native weights at the head of ws
    bf16_t* WqF = (bf16_t*)d_ws;
    bf16_t* WkF = WqF + 16384;
    bf16_t* WvF = WkF + 16384;
    bf16_t* WoF = WvF + 16384;

    pack_w<<<dim3(NH), 256, 0, stream>>>(Wq, Wk, Wv, Wo, WqF, WkF, WvF, WoF);
    hipMemsetAsync(d_out, 0, (size_t)out_size, stream);  // atomic-accumulate base
    fused_sb<<<dim3(1024), 256, 0, stream>>>(Xq, Xkv, Mask, Bias,
                                             WqF, WkF, WvF, WoF, Bo, Out);
}

// Round 8
// 148.897 us; speedup vs baseline: 1.1252x; 1.0669x over previous
//
#include <hip/hip_runtime.h>

typedef __bf16 bf16_t;
typedef __bf16 bf16x4_t __attribute__((ext_vector_type(4)));
typedef __bf16 bf16x8 __attribute__((ext_vector_type(8)));
typedef float f32x4 __attribute__((ext_vector_type(4)));

#define NH 8
#define DH 32
#define QL 256
#define KL 256
#define CIN 64
#define HD 256  // NH*DH

__device__ __forceinline__ bf16_t f2bf(float x) { return (bf16_t)x; }

__device__ __forceinline__ f32x4 mfma16(bf16x8 a, bf16x8 b, f32x4 c) {
    return __builtin_amdgcn_mfma_f32_16x16x32_bf16(a, b, c, 0, 0, 0);
}

// ---------------------------------------------------------------------------
// pack_w: one-time repack of Wq/Wk/Wv/Wo into fragment-native bf16 layout.
// Frag elem j at lane(quad,l16):
//   WqF/WkF/WvF: W[ks*32+quad*8+j][h*32 + nt*16 + l16]   (B-operand, proj)
//   WoF:         Wo[h*32+quad*8+j][nt*16 + l16]          (B-operand, outproj)
__launch_bounds__(256)
__global__ void pack_w(const float* __restrict__ Wq, const float* __restrict__ Wk,
                       const float* __restrict__ Wv, const float* __restrict__ Wo,
                       bf16_t* __restrict__ WqF, bf16_t* __restrict__ WkF,
                       bf16_t* __restrict__ WvF, bf16_t* __restrict__ WoF) {
    const int h = blockIdx.x;
    const int tid = threadIdx.x, lane = tid & 63, w = tid >> 6;
    const int quad = lane >> 4, l16 = lane & 15;
    if (w < 3) {
        const float* __restrict__ W = (w == 0) ? Wq : (w == 1 ? Wk : Wv);
        bf16_t* __restrict__ F = (w == 0) ? WqF : (w == 1 ? WkF : WvF);
#pragma unroll
        for (int nt = 0; nt < 2; ++nt)
#pragma unroll
            for (int ks = 0; ks < 2; ++ks) {
                bf16x8 f;
#pragma unroll
                for (int j = 0; j < 8; ++j)
                    f[j] = f2bf(W[(ks * 32 + quad * 8 + j) * HD + h * DH + nt * 16 + l16]);
                *(bf16x8*)&F[(size_t)((h * 4 + nt * 2 + ks) * 512) + lane * 8] = f;
            }
    } else {
#pragma unroll
        for (int nt = 0; nt < 4; ++nt) {
            bf16x8 f;
#pragma unroll
            for (int j = 0; j < 8; ++j)
                f[j] = f2bf(Wo[(h * DH + quad * 8 + j) * CIN + nt * 16 + l16]);
            *(bf16x8*)&WoF[(size_t)((h * 4 + nt) * 512) + lane * 8] = f;
        }
    }
}

// ---------------------------------------------------------------------------
// fused_g2: r5's best structure (512 blocks, 1-barrier-rate dbuf pipeline,
// 61.8 us) with TWO HEADS PER PHASE for doubled ILP. r5 post-mortem: 2
// waves/SIMD + barrier lockstep leaves the softmax chain + 6 same-wave LDS
// round-trips exposed (~60% idle); r7 proved occupancy can't be bought with
// barriers. So each wave now carries two independent head-streams:
//   phase i: QK(2i)+QK(2i+1) | B1 | projK(2i+2/3) filler | softmax x2
//   interleaved | PV x2 (sPT-pipelined 8 deep) | B2 | projV(2i+2/3) |
//   outproj x2 | projQ x2 + bias-prefetch x2 tail.
// Head-parity-pinned buffers (even->buf0, odd->buf1). Same 9 barriers, same
// 75 KB LDS, ALL index math r5-verbatim (r4/r6 lesson: no new bank math).
__launch_bounds__(256, 2)
__global__ void fused_g2(const float* __restrict__ Xq, const float* __restrict__ Xkv,
                         const float* __restrict__ Mask, const float* __restrict__ Bias,
                         const bf16_t* __restrict__ WqF, const bf16_t* __restrict__ WkF,
                         const bf16_t* __restrict__ WvF, const bf16_t* __restrict__ WoF,
                         const float* __restrict__ Bo, float* __restrict__ Out) {
    const int b = blockIdx.x;
    const int s = b & 127, qq = b >> 7;   // s fastest: XCD = s&7 (Xkv/Out locality)
    const int tid = threadIdx.x, lane = tid & 63, w = tid >> 6;
    const int quad = lane >> 4, l16 = lane & 15;
    const int tg = qq * 4 + w;            // this wave's global q-tile (16 rows)
    const f32x4 vzero = {0.f, 0.f, 0.f, 0.f};

    __shared__ __attribute__((aligned(16))) bf16_t sK[2][KL * 32];   // 32 KB, swz (r5)
    __shared__ __attribute__((aligned(16))) bf16_t sVT[2][DH][264];  // 33 KB (r5)
    __shared__ __attribute__((aligned(16))) bf16_t sPT[4][16][72];   //  9 KB bounce (r5)
    __shared__ __attribute__((aligned(16))) float sMask[KL];         //  1 KB

    if (tid < 64) {
        const f32x4 m4 = *(const f32x4*)&Mask[s * KL + tid * 4];
        f32x4 mm;
#pragma unroll
        for (int j = 0; j < 4; ++j) mm[j] = (m4[j] - 1.0f) * 1.0e9f;
        *(f32x4*)&sMask[tid * 4] = mm;
    }

    // ---- X fragments, register-resident for all 8 heads ----
    bf16x8 xk[4][2];  // Xkv A-frags: wave owns kv-tiles {4w..4w+3}
#pragma unroll
    for (int t = 0; t < 4; ++t) {
        const int row = (w * 4 + t) * 16 + l16;
        const float* src = &Xkv[(size_t)(s * QL + row) * CIN];
#pragma unroll
        for (int ks = 0; ks < 2; ++ks) {
            const f32x4 lo = *(const f32x4*)&src[ks * 32 + quad * 8];
            const f32x4 hi = *(const f32x4*)&src[ks * 32 + quad * 8 + 4];
            bf16x8 f;
#pragma unroll
            for (int j = 0; j < 4; ++j) { f[j] = f2bf(lo[j]); f[4 + j] = f2bf(hi[j]); }
            xk[t][ks] = f;
        }
    }
    bf16x8 xq[2];  // Xq A-frags for this wave's q-tile, pre-scaled 1/sqrt(32)
    {
        const int row = tg * 16 + l16;
        const float* src = &Xq[(size_t)(s * QL + row) * CIN];
#pragma unroll
        for (int ks = 0; ks < 2; ++ks) {
            const f32x4 lo = *(const f32x4*)&src[ks * 32 + quad * 8];
            const f32x4 hi = *(const f32x4*)&src[ks * 32 + quad * 8 + 4];
            bf16x8 f;
#pragma unroll
            for (int j = 0; j < 4; ++j) {
                f[j] = f2bf(lo[j] * 0.17677669529663687f);
                f[4 + j] = f2bf(hi[j] * 0.17677669529663687f);
            }
            xq[ks] = f;
        }
    }

    // K projection of head h -> swizzled sK[buf] (r5-proven indexing)
    auto projK = [&](int h, int buf) {
        bf16x8 bk[2][2];
#pragma unroll
        for (int nt = 0; nt < 2; ++nt)
#pragma unroll
            for (int ks = 0; ks < 2; ++ks)
                bk[nt][ks] = *(const bf16x8*)&WkF[(size_t)((h * 4 + nt * 2 + ks) * 512) + lane * 8];
#pragma unroll
        for (int t = 0; t < 4; ++t) {
            const int r0 = (w * 4 + t) * 16 + quad * 4;
#pragma unroll
            for (int nt = 0; nt < 2; ++nt) {
                f32x4 c = mfma16(xk[t][0], bk[nt][0], vzero);
                c = mfma16(xk[t][1], bk[nt][1], c);
                const int chS = ((nt * 2 + (l16 >> 3)) ^ quad) << 3;
#pragma unroll
                for (int r = 0; r < 4; ++r)
                    sK[buf][(r0 + r) * 32 + chS + (l16 & 7)] = f2bf(c[r]);
            }
        }
    };
    // V projection of head h -> sVT[buf] transpose-store (r5-proven indexing)
    auto projV = [&](int h, int buf) {
        bf16x8 bv[2][2];
#pragma unroll
        for (int nt = 0; nt < 2; ++nt)
#pragma unroll
            for (int ks = 0; ks < 2; ++ks)
                bv[nt][ks] = *(const bf16x8*)&WvF[(size_t)((h * 4 + nt * 2 + ks) * 512) + lane * 8];
#pragma unroll
        for (int t = 0; t < 4; ++t) {
            const int c0 = (w * 4 + t) * 16 + quad * 4;
#pragma unroll
            for (int nt = 0; nt < 2; ++nt) {
                f32x4 c = mfma16(xk[t][0], bv[nt][0], vzero);
                c = mfma16(xk[t][1], bv[nt][1], c);
                bf16x4_t p4;
#pragma unroll
                for (int r = 0; r < 4; ++r) p4[r] = f2bf(c[r]);
                *(bf16x4_t*)&sVT[buf][nt * 16 + l16][c0] = p4;
            }
        }
    };
    // Q projection (per-wave sPT bounce, same-wave DS order; r5-proven)
    auto projQ = [&](int h) -> bf16x8 {
        bf16x8 bq[2][2];
#pragma unroll
        for (int nt = 0; nt < 2; ++nt)
#pragma unroll
            for (int ks = 0; ks < 2; ++ks)
                bq[nt][ks] = *(const bf16x8*)&WqF[(size_t)((h * 4 + nt * 2 + ks) * 512) + lane * 8];
#pragma unroll
        for (int nt = 0; nt < 2; ++nt) {
            f32x4 c = mfma16(xq[0], bq[nt][0], vzero);
            c = mfma16(xq[1], bq[nt][1], c);
#pragma unroll
            for (int r = 0; r < 4; ++r) sPT[w][quad * 4 + r][nt * 16 + l16] = f2bf(c[r]);
        }
        return *(const bf16x8*)&sPT[w][l16][quad * 8];
    };

    f32x4 acc[4];  // output accumulator (summed over ALL heads)
#pragma unroll
    for (int nt = 0; nt < 4; ++nt) acc[nt] = vzero;

    // ---- prologue: bias(0,1) in flight; K/V/Q for heads 0,1 ----
    f32x4 sv[2][16];
#pragma unroll
    for (int u = 0; u < 2; ++u) {
        const float* bb = &Bias[(size_t)(u * QL + tg * 16 + l16) * KL];
#pragma unroll
        for (int ct = 0; ct < 16; ++ct) sv[u][ct] = *(const f32x4*)&bb[ct * 16 + quad * 4];
    }
    projK(0, 0);
    projK(1, 1);
    projV(0, 0);
    projV(1, 1);
    bf16x8 qfr0 = projQ(0);
    bf16x8 qfr1 = projQ(1);
    __syncthreads();  // bufs + sMask visible

#pragma unroll 1
    for (int i = 0; i < 4; ++i) {
        const int h0 = 2 * i, h1 = 2 * i + 1;

        // ---- QK both heads (32 independent MFMAs; bias rides C) ----
#pragma unroll
        for (int ct = 0; ct < 16; ++ct) {
            const int row = ct * 16 + l16;
            const int chS = (quad ^ ((l16 >> 2) & 3)) << 3;
            const bf16x8 ak0 = *(const bf16x8*)&sK[0][row * 32 + chS];
            const bf16x8 ak1 = *(const bf16x8*)&sK[1][row * 32 + chS];
            sv[0][ct] = mfma16(ak0, qfr0, sv[0][ct]);
            sv[1][ct] = mfma16(ak1, qfr1, sv[1][ct]);
        }

        __syncthreads();  // B1: all waves done reading sK[0/1]

        // ---- projK(h+2) filler overwrites sK while softmax runs ----
        if (i < 3) {
            projK(h0 + 2, 0);
            projK(h1 + 2, 1);
        }

        // ---- mask add (shared reads) + two interleaved softmax chains ----
        f32x4 vmx0, vmx1;
        {
            const f32x4 m0 = *(const f32x4*)&sMask[0 * 16 + quad * 4];
            sv[0][0] += m0;
            sv[1][0] += m0;
            vmx0 = sv[0][0];
            vmx1 = sv[1][0];
        }
#pragma unroll
        for (int ct = 1; ct < 16; ++ct) {
            const f32x4 mm = *(const f32x4*)&sMask[ct * 16 + quad * 4];
            sv[0][ct] += mm;
            sv[1][ct] += mm;
#pragma unroll
            for (int r = 0; r < 4; ++r) {
                vmx0[r] = fmaxf(vmx0[r], sv[0][ct][r]);
                vmx1[r] = fmaxf(vmx1[r], sv[1][ct][r]);
            }
        }
        float mx0 = fmaxf(fmaxf(vmx0[0], vmx0[1]), fmaxf(vmx0[2], vmx0[3]));
        float mx1 = fmaxf(fmaxf(vmx1[0], vmx1[1]), fmaxf(vmx1[2], vmx1[3]));
        mx0 = fmaxf(mx0, __shfl_xor(mx0, 16, 64));
        mx1 = fmaxf(mx1, __shfl_xor(mx1, 16, 64));
        mx0 = fmaxf(mx0, __shfl_xor(mx0, 32, 64));
        mx1 = fmaxf(mx1, __shfl_xor(mx1, 32, 64));
        f32x4 vs0 = vzero, vs1 = vzero;
#pragma unroll
        for (int ct = 0; ct < 16; ++ct)
#pragma unroll
            for (int r = 0; r < 4; ++r) {
                const float e0 = __expf(sv[0][ct][r] - mx0);
                const float e1 = __expf(sv[1][ct][r] - mx1);
                sv[0][ct][r] = e0;
                sv[1][ct][r] = e1;
                vs0[r] += e0;
                vs1[r] += e1;
            }
        float sum0 = (vs0[0] + vs0[1]) + (vs0[2] + vs0[3]);
        float sum1 = (vs1[0] + vs1[1]) + (vs1[2] + vs1[3]);
        sum0 += __shfl_xor(sum0, 16, 64);
        sum1 += __shfl_xor(sum1, 16, 64);
        sum0 += __shfl_xor(sum0, 32, 64);
        sum1 += __shfl_xor(sum1, 32, 64);
        const float rs0 = 1.0f / sum0;
        const float rs1 = 1.0f / sum1;

        // ---- PV both heads, pipelined through the shared sPT bounce ----
        f32x4 o00 = vzero, o01 = vzero, o10 = vzero, o11 = vzero;
#pragma unroll
        for (int c = 0; c < 4; ++c) {
            // head h0 chunk c
#pragma unroll
            for (int cc = 0; cc < 4; ++cc) {
                const int ct = c * 4 + cc;
                bf16x4_t pv;
#pragma unroll
                for (int r = 0; r < 4; ++r) pv[r] = f2bf(sv[0][ct][r] * rs0);
                *(bf16x4_t*)&sPT[w][l16][cc * 16 + quad * 4] = pv;
            }
#pragma unroll
            for (int ks = 0; ks < 2; ++ks) {
                const bf16x8 ap = *(const bf16x8*)&sPT[w][l16][ks * 32 + quad * 8];
                const int cs = c * 2 + ks;
                const bf16x8 v0 = *(const bf16x8*)&sVT[0][l16][cs * 32 + quad * 8];
                const bf16x8 v1 = *(const bf16x8*)&sVT[0][16 + l16][cs * 32 + quad * 8];
                o00 = mfma16(ap, v0, o00);
                o01 = mfma16(ap, v1, o01);
            }
            // head h1 chunk c (same-wave DS ordering guards the reuse)
#pragma unroll
            for (int cc = 0; cc < 4; ++cc) {
                const int ct = c * 4 + cc;
                bf16x4_t pv;
#pragma unroll
                for (int r = 0; r < 4; ++r) pv[r] = f2bf(sv[1][ct][r] * rs1);
                *(bf16x4_t*)&sPT[w][l16][cc * 16 + quad * 4] = pv;
            }
#pragma unroll
            for (int ks = 0; ks < 2; ++ks) {
                const bf16x8 ap = *(const bf16x8*)&sPT[w][l16][ks * 32 + quad * 8];
                const int cs = c * 2 + ks;
                const bf16x8 v0 = *(const bf16x8*)&sVT[1][l16][cs * 32 + quad * 8];
                const bf16x8 v1 = *(const bf16x8*)&sVT[1][16 + l16][cs * 32 + quad * 8];
                o10 = mfma16(ap, v0, o10);
                o11 = mfma16(ap, v1, o11);
            }
        }

        __syncthreads();  // B2: sVT free (PV done); sK(h+2/3) visible for next QK

        // ---- projV(h+2) overwrites sVT (visible by next phase's B1) ----
        if (i < 3) {
            projV(h0 + 2, 0);
            projV(h1 + 2, 1);
        }

        // ---- outproj both heads via per-wave sPT bounce ----
        {
            bf16x8 bwo[4];
#pragma unroll
            for (int nt = 0; nt < 4; ++nt)
                bwo[nt] = *(const bf16x8*)&WoF[(size_t)((h0 * 4 + nt) * 512) + lane * 8];
#pragma unroll
            for (int r = 0; r < 4; ++r) {
                sPT[w][quad * 4 + r][l16] = f2bf(o00[r]);
                sPT[w][quad * 4 + r][16 + l16] = f2bf(o01[r]);
            }
            const bf16x8 af = *(const bf16x8*)&sPT[w][l16][quad * 8];
#pragma unroll
            for (int nt = 0; nt < 4; ++nt) acc[nt] = mfma16(af, bwo[nt], acc[nt]);
        }
        {
            bf16x8 bwo[4];
#pragma unroll
            for (int nt = 0; nt < 4; ++nt)
                bwo[nt] = *(const bf16x8*)&WoF[(size_t)((h1 * 4 + nt) * 512) + lane * 8];
#pragma unroll
            for (int r = 0; r < 4; ++r) {
                sPT[w][quad * 4 + r][l16] = f2bf(o10[r]);
                sPT[w][quad * 4 + r][16 + l16] = f2bf(o11[r]);
            }
            const bf16x8 af = *(const bf16x8*)&sPT[w][l16][quad * 8];
#pragma unroll
            for (int nt = 0; nt < 4; ++nt) acc[nt] = mfma16(af, bwo[nt], acc[nt]);
        }

        // ---- tail: Q(h+2/3) + bias(h+2/3) into sv (dead after PV) ----
        if (i < 3) {
            qfr0 = projQ(h0 + 2);
            qfr1 = projQ(h1 + 2);
#pragma unroll
            for (int u = 0; u < 2; ++u) {
                const float* bb = &Bias[(size_t)((h0 + 2 + u) * QL + tg * 16 + l16) * KL];
#pragma unroll
                for (int ct = 0; ct < 16; ++ct)
                    sv[u][ct] = *(const f32x4*)&bb[ct * 16 + quad * 4];
            }
        }
        // no extra barrier: next QK reads sK (covered by B2); next PV reads
        // sVT written above (covered by next phase's B1).
    }

    // -------------------- epilogue: direct store --------------------
    const int orow = s * QL + tg * 16 + quad * 4;
#pragma unroll
    for (int nt = 0; nt < 4; ++nt) {
        const float bo = Bo[nt * 16 + l16];
#pragma unroll
        for (int r = 0; r < 4; ++r)
            Out[(size_t)(orow + r) * CIN + nt * 16 + l16] = acc[nt][r] + bo;
    }
}

extern "C" void kernel_launch(void* const* d_in, const int* in_sizes, int n_in,
                              void* d_out, int out_size, void* d_ws, size_t ws_size,
                              hipStream_t stream) {
    const float* Xq   = (const float*)d_in[0];
    const float* Xkv  = (const float*)d_in[1];
    const float* Mask = (const float*)d_in[2];
    const float* Bias = (const float*)d_in[3];
    const float* Wq   = (const float*)d_in[4];
    const float* Wk   = (const float*)d_in[5];
    const float* Wv   = (const float*)d_in[6];
    const float* Wo   = (const float*)d_in[7];
    const float* Bo   = (const float*)d_in[8];
    float* Out = (float*)d_out;

    // 128 KB of fragment-native weights at the head of ws
    bf16_t* WqF = (bf16_t*)d_ws;
    bf16_t* WkF = WqF + 16384;
    bf16_t* WvF = WkF + 16384;
    bf16_t* WoF = WvF + 16384;

    pack_w<<<dim3(NH), 256, 0, stream>>>(Wq, Wk, Wv, Wo, WqF, WkF, WvF, WoF);
    fused_g2<<<dim3(512), 256, 0, stream>>>(Xq, Xkv, Mask, Bias,
                                            WqF, WkF, WvF, WoF, Bo, Out);
}

// Round 9
// 139.415 us; speedup vs baseline: 1.2017x; 1.0680x over previous
//
#include <hip/hip_runtime.h>

typedef __bf16 bf16_t;
typedef __bf16 bf16x4_t __attribute__((ext_vector_type(4)));
typedef __bf16 bf16x8 __attribute__((ext_vector_type(8)));
typedef float f32x4 __attribute__((ext_vector_type(4)));

#define NH 8
#define DH 32
#define QL 256
#define KL 256
#define CIN 64
#define HD 256  // NH*DH

__device__ __forceinline__ bf16_t f2bf(float x) { return (bf16_t)x; }

__device__ __forceinline__ f32x4 mfma16(bf16x8 a, bf16x8 b, f32x4 c) {
    return __builtin_amdgcn_mfma_f32_16x16x32_bf16(a, b, c, 0, 0, 0);
}

// raw v_exp_f32: D = 2^S0 (gfx9-lineage VALU is HW-interlocked)
__device__ __forceinline__ float exp2_raw(float x) {
    float r;
    asm("v_exp_f32 %0, %1" : "=v"(r) : "v"(x));
    return r;
}

// ---------------------------------------------------------------------------
// pack_w: one-time repack of Wq/Wk/Wv/Wo into fragment-native bf16 layout.
// Frag elem j at lane(quad,l16):
//   WqF/WkF/WvF: W[ks*32+quad*8+j][h*32 + nt*16 + l16]          (B-op, proj)
//   WoF (r9, delta-packed): Wo[h*32 + (j>>2)*16 + quad*4 + (j&3)][nt*16+l16]
//     -- the outproj k-sum is relabeled d <- delta(k) so the O A-frag is
//        lane-local from swapped-PV output (no LDS bounce).
__launch_bounds__(256)
__global__ void pack_w(const float* __restrict__ Wq, const float* __restrict__ Wk,
                       const float* __restrict__ Wv, const float* __restrict__ Wo,
                       bf16_t* __restrict__ WqF, bf16_t* __restrict__ WkF,
                       bf16_t* __restrict__ WvF, bf16_t* __restrict__ WoF) {
    const int h = blockIdx.x;
    const int tid = threadIdx.x, lane = tid & 63, w = tid >> 6;
    const int quad = lane >> 4, l16 = lane & 15;
    if (w < 3) {
        const float* __restrict__ W = (w == 0) ? Wq : (w == 1 ? Wk : Wv);
        bf16_t* __restrict__ F = (w == 0) ? WqF : (w == 1 ? WkF : WvF);
#pragma unroll
        for (int nt = 0; nt < 2; ++nt)
#pragma unroll
            for (int ks = 0; ks < 2; ++ks) {
                bf16x8 f;
#pragma unroll
                for (int j = 0; j < 8; ++j)
                    f[j] = f2bf(W[(ks * 32 + quad * 8 + j) * HD + h * DH + nt * 16 + l16]);
                *(bf16x8*)&F[(size_t)((h * 4 + nt * 2 + ks) * 512) + lane * 8] = f;
            }
    } else {
#pragma unroll
        for (int nt = 0; nt < 4; ++nt) {
            bf16x8 f;
#pragma unroll
            for (int j = 0; j < 8; ++j)
                f[j] = f2bf(Wo[(h * DH + (j >> 2) * 16 + quad * 4 + (j & 3)) * CIN +
                               nt * 16 + l16]);
            *(bf16x8*)&WoF[(size_t)((h * 4 + nt) * 512) + lane * 8] = f;
        }
    }
}

// ---------------------------------------------------------------------------
// fused_pipe3: r5's champion structure (512 blocks, dbuf, 1 barrier/head)
// with the in-wave LDS round-trips deleted:
//  (1) swapped PV + sigma k-relabel: O^T = mfma(V^T-frag, P-frag) where
//      sigma(c,k)=32c+16*((k>>2)&1)+4*quad+(k&3) makes the P B-frag
//      LANE-LOCAL (pf = bf16 of sv[2c],[2c+1]) -- P^T staging gone.
//      V^T A-frags = 2x b64 from the UNCHANGED proven sVT layout.
//  (2) delta-packed outproj (see pack_w): O A-frag lane-local from ot[]
//      -- O bounce gone. Only Q's bounce remains (tail, off-path).
//  (3) 1/sum folded into outproj A-frag: sum-reduce+div hide under PV.
//  (4) log2e folded into Q-scale/bias/mask; exp = raw v_exp_f32 (2^x);
//      mask pre-added to bias in the tail -> QK starts the phase cold.
__launch_bounds__(256, 2)
__global__ void fused_pipe3(const float* __restrict__ Xq, const float* __restrict__ Xkv,
                            const float* __restrict__ Mask, const float* __restrict__ Bias,
                            const bf16_t* __restrict__ WqF, const bf16_t* __restrict__ WkF,
                            const bf16_t* __restrict__ WvF, const bf16_t* __restrict__ WoF,
                            const float* __restrict__ Bo, float* __restrict__ Out) {
    const int b = blockIdx.x;
    const int s = b & 127, qq = b >> 7;   // s fastest: same-s blocks share an XCD
    const int tid = threadIdx.x, lane = tid & 63, w = tid >> 6;
    const int quad = lane >> 4, l16 = lane & 15;
    const int tg = qq * 4 + w;            // this wave's global q-tile (16 rows)
    const f32x4 vzero = {0.f, 0.f, 0.f, 0.f};
    constexpr float L2E = 1.4426950408889634f;

    __shared__ __attribute__((aligned(16))) bf16_t sK[2][KL * 32];   // 32 KB dbuf, swz (r5)
    __shared__ __attribute__((aligned(16))) bf16_t sVT[2][DH][264];  // 33 KB dbuf (r5)
    __shared__ __attribute__((aligned(16))) bf16_t sPT[4][16][72];   //  9 KB Q bounce (r5)
    __shared__ __attribute__((aligned(16))) float sMask[KL];         //  1 KB

    // mask pre-combined AND pre-scaled by log2e: (m-1)*1e9*L2E
    if (tid < 64) {
        const f32x4 m4 = *(const f32x4*)&Mask[s * KL + tid * 4];
        f32x4 mm;
#pragma unroll
        for (int j = 0; j < 4; ++j) mm[j] = (m4[j] - 1.0f) * (1.0e9f * L2E);
        *(f32x4*)&sMask[tid * 4] = mm;
    }

    // ---- X fragments, register-resident for all 8 heads ----
    bf16x8 xk[4][2];  // Xkv A-frags: wave owns kv-tiles {4w..4w+3}
#pragma unroll
    for (int t = 0; t < 4; ++t) {
        const int row = (w * 4 + t) * 16 + l16;
        const float* src = &Xkv[(size_t)(s * QL + row) * CIN];
#pragma unroll
        for (int ks = 0; ks < 2; ++ks) {
            const f32x4 lo = *(const f32x4*)&src[ks * 32 + quad * 8];
            const f32x4 hi = *(const f32x4*)&src[ks * 32 + quad * 8 + 4];
            bf16x8 f;
#pragma unroll
            for (int j = 0; j < 4; ++j) { f[j] = f2bf(lo[j]); f[4 + j] = f2bf(hi[j]); }
            xk[t][ks] = f;
        }
    }
    bf16x8 xq[2];  // Xq A-frags, pre-scaled by (1/sqrt(32))*log2(e)
    {
        const int row = tg * 16 + l16;
        const float* src = &Xq[(size_t)(s * QL + row) * CIN];
        const float qs = 0.17677669529663687f * L2E;
#pragma unroll
        for (int ks = 0; ks < 2; ++ks) {
            const f32x4 lo = *(const f32x4*)&src[ks * 32 + quad * 8];
            const f32x4 hi = *(const f32x4*)&src[ks * 32 + quad * 8 + 4];
            bf16x8 f;
#pragma unroll
            for (int j = 0; j < 4; ++j) {
                f[j] = f2bf(lo[j] * qs);
                f[4 + j] = f2bf(hi[j] * qs);
            }
            xq[ks] = f;
        }
    }

    // K/V projection of head h into LDS buffer buf (r5-verbatim indexing)
    auto projKV = [&](int h, int buf) {
        bf16x8 bk[2][2], bv[2][2];
#pragma unroll
        for (int nt = 0; nt < 2; ++nt)
#pragma unroll
            for (int ks = 0; ks < 2; ++ks) {
                bk[nt][ks] = *(const bf16x8*)&WkF[(size_t)((h * 4 + nt * 2 + ks) * 512) + lane * 8];
                bv[nt][ks] = *(const bf16x8*)&WvF[(size_t)((h * 4 + nt * 2 + ks) * 512) + lane * 8];
            }
#pragma unroll
        for (int t = 0; t < 4; ++t) {
            const int r0 = (w * 4 + t) * 16 + quad * 4;
#pragma unroll
            for (int nt = 0; nt < 2; ++nt) {
                f32x4 c = mfma16(xk[t][0], bk[nt][0], vzero);
                c = mfma16(xk[t][1], bk[nt][1], c);
                const int chS = ((nt * 2 + (l16 >> 3)) ^ quad) << 3;
#pragma unroll
                for (int r = 0; r < 4; ++r)
                    sK[buf][(r0 + r) * 32 + chS + (l16 & 7)] = f2bf(c[r]);
            }
        }
#pragma unroll
        for (int t = 0; t < 4; ++t) {
            const int c0 = (w * 4 + t) * 16 + quad * 4;
#pragma unroll
            for (int nt = 0; nt < 2; ++nt) {
                f32x4 c = mfma16(xk[t][0], bv[nt][0], vzero);
                c = mfma16(xk[t][1], bv[nt][1], c);
                bf16x4_t p4;
#pragma unroll
                for (int r = 0; r < 4; ++r) p4[r] = f2bf(c[r]);
                *(bf16x4_t*)&sVT[buf][nt * 16 + l16][c0] = p4;
            }
        }
    };
    // Q projection (per-wave sPT bounce, same-wave DS order; r5-verbatim)
    auto projQ = [&](int h) -> bf16x8 {
        bf16x8 bq[2][2];
#pragma unroll
        for (int nt = 0; nt < 2; ++nt)
#pragma unroll
            for (int ks = 0; ks < 2; ++ks)
                bq[nt][ks] = *(const bf16x8*)&WqF[(size_t)((h * 4 + nt * 2 + ks) * 512) + lane * 8];
#pragma unroll
        for (int nt = 0; nt < 2; ++nt) {
            f32x4 c = mfma16(xq[0], bq[nt][0], vzero);
            c = mfma16(xq[1], bq[nt][1], c);
#pragma unroll
            for (int r = 0; r < 4; ++r) sPT[w][quad * 4 + r][nt * 16 + l16] = f2bf(c[r]);
        }
        return *(const bf16x8*)&sPT[w][l16][quad * 8];
    };

    f32x4 acc[4];  // output accumulator: 16 q-rows x 64 out-cols
#pragma unroll
    for (int nt = 0; nt < 4; ++nt) acc[nt] = vzero;

    // ---- prologue: bias(0) in flight, K/V(0) -> buf0, qfr(0) ready ----
    f32x4 sv[16];
    {
        const float* bb = &Bias[(size_t)(tg * 16 + l16) * KL];
#pragma unroll
        for (int ct = 0; ct < 16; ++ct) sv[ct] = *(const f32x4*)&bb[ct * 16 + quad * 4];
    }
    projKV(0, 0);
    bf16x8 qfr = projQ(0);
    __syncthreads();  // buf0 + sMask visible
#pragma unroll
    for (int ct = 0; ct < 16; ++ct) {
        const f32x4 m4 = *(const f32x4*)&sMask[ct * 16 + quad * 4];
#pragma unroll
        for (int r = 0; r < 4; ++r) sv[ct][r] = sv[ct][r] * L2E + m4[r];
    }

#pragma unroll 1
    for (int h = 0; h < NH; ++h) {
        const int p = h & 1;

        // ---- QK immediately: qfr + sv(=(bias+mask)*L2E) ready ----
#pragma unroll
        for (int ct = 0; ct < 16; ++ct) {
            const int row = ct * 16 + l16;
            const int chS = (quad ^ ((l16 >> 2) & 3)) << 3;
            const bf16x8 ak = *(const bf16x8*)&sK[p][row * 32 + chS];
            sv[ct] = mfma16(ak, qfr, sv[ct]);  // S' = S*log2e, bias+mask included
        }

        // ---- proj(h+1) into buf 1-p: independent MFMA filler ----
        if (h + 1 < NH) projKV(h + 1, p ^ 1);

        // ---- Wo frags (delta-packed; global, L2-hot; used at phase end) ----
        bf16x8 bwo[4];
#pragma unroll
        for (int nt = 0; nt < 4; ++nt)
            bwo[nt] = *(const bf16x8*)&WoF[(size_t)((h * 4 + nt) * 512) + lane * 8];

        // ---- softmax in exp2 domain (tree-reduced max; raw v_exp_f32) ----
        f32x4 vmx = sv[0];
#pragma unroll
        for (int ct = 1; ct < 16; ++ct)
#pragma unroll
            for (int r = 0; r < 4; ++r) vmx[r] = fmaxf(vmx[r], sv[ct][r]);
        float mx = fmaxf(fmaxf(vmx[0], vmx[1]), fmaxf(vmx[2], vmx[3]));
        mx = fmaxf(mx, __shfl_xor(mx, 16, 64));
        mx = fmaxf(mx, __shfl_xor(mx, 32, 64));
        f32x4 vsum = vzero;
#pragma unroll
        for (int ct = 0; ct < 16; ++ct)
#pragma unroll
            for (int r = 0; r < 4; ++r) {
                const float e = exp2_raw(sv[ct][r] - mx);
                sv[ct][r] = e;
                vsum[r] += e;
            }
        float sum = (vsum[0] + vsum[1]) + (vsum[2] + vsum[3]);
        sum += __shfl_xor(sum, 16, 64);
        sum += __shfl_xor(sum, 32, 64);
        const float rs = 1.0f / sum;  // consumed only after PV -> hides under it

        // ---- swapped PV, LDS-free P: O^T = mfma(V^T-frag, P-frag) ----
        // sigma(c,k)=32c+16*((k>>2)&1)+4*quad+(k&3):
        //   B-frag pf[j] = sv[2c + (j>>2)][j&3]           (lane-local!)
        //   A-frag va[j] = sVT[d][32c + (j>>2)*16 + quad*4 + (j&3)] (2x b64)
        f32x4 ot0 = vzero, ot1 = vzero;
#pragma unroll
        for (int c = 0; c < 8; ++c) {
            bf16x8 pf;
#pragma unroll
            for (int j = 0; j < 4; ++j) {
                pf[j] = f2bf(sv[2 * c][j]);
                pf[4 + j] = f2bf(sv[2 * c + 1][j]);
            }
            const bf16x4_t a00 = *(const bf16x4_t*)&sVT[p][l16][c * 32 + quad * 4];
            const bf16x4_t a01 = *(const bf16x4_t*)&sVT[p][l16][c * 32 + 16 + quad * 4];
            const bf16x4_t a10 = *(const bf16x4_t*)&sVT[p][16 + l16][c * 32 + quad * 4];
            const bf16x4_t a11 = *(const bf16x4_t*)&sVT[p][16 + l16][c * 32 + 16 + quad * 4];
            bf16x8 va0, va1;
#pragma unroll
            for (int j = 0; j < 4; ++j) {
                va0[j] = a00[j];
                va0[4 + j] = a01[j];
                va1[j] = a10[j];
                va1[4 + j] = a11[j];
            }
            ot0 = mfma16(va0, pf, ot0);  // O^T[d=quad*4+r][q=l16], d-tile 0
            ot1 = mfma16(va1, pf, ot1);  // d-tile 1
        }

        // ---- bias(h+1) early issue into sv (dead after pf; zero extra regs) ----
        if (h + 1 < NH) {
            const float* bb = &Bias[(size_t)((h + 1) * QL + tg * 16 + l16) * KL];
#pragma unroll
            for (int ct = 0; ct < 16; ++ct) sv[ct] = *(const f32x4*)&bb[ct * 16 + quad * 4];
        }

        // ---- outproj, LDS-free O: af[j] = ot[j>>2][j&3]*rs (delta-packed Wo) ----
        {
            bf16x8 af;
#pragma unroll
            for (int r = 0; r < 4; ++r) {
                af[r] = f2bf(ot0[r] * rs);
                af[4 + r] = f2bf(ot1[r] * rs);
            }
#pragma unroll
            for (int nt = 0; nt < 4; ++nt) acc[nt] = mfma16(af, bwo[nt], acc[nt]);
        }

        // ---- tail: Q(h+1); fold mask into prefetched bias ----
        if (h + 1 < NH) {
            qfr = projQ(h + 1);
#pragma unroll
            for (int ct = 0; ct < 16; ++ct) {
                const f32x4 m4 = *(const f32x4*)&sMask[ct * 16 + quad * 4];
#pragma unroll
                for (int r = 0; r < 4; ++r) sv[ct][r] = sv[ct][r] * L2E + m4[r];
            }
        }

        __syncthreads();  // single barrier/head: buf 1-p ready, buf p free
    }

    // -------------------- epilogue: direct store --------------------
    const int orow = s * QL + tg * 16 + quad * 4;
#pragma unroll
    for (int nt = 0; nt < 4; ++nt) {
        const float bo = Bo[nt * 16 + l16];
#pragma unroll
        for (int r = 0; r < 4; ++r)
            Out[(size_t)(orow + r) * CIN + nt * 16 + l16] = acc[nt][r] + bo;
    }
}

extern "C" void kernel_launch(void* const* d_in, const int* in_sizes, int n_in,
                              void* d_out, int out_size, void* d_ws, size_t ws_size,
                              hipStream_t stream) {
    const float* Xq   = (const float*)d_in[0];
    const float* Xkv  = (const float*)d_in[1];
    const float* Mask = (const float*)d_in[2];
    const float* Bias = (const float*)d_in[3];
    const float* Wq   = (const float*)d_in[4];
    const float* Wk   = (const float*)d_in[5];
    const float* Wv   = (const float*)d_in[6];
    const float* Wo   = (const float*)d_in[7];
    const float* Bo   = (const float*)d_in[8];
    float* Out = (float*)d_out;

    // 128 KB of fragment-native weights at the head of ws
    bf16_t* WqF = (bf16_t*)d_ws;
    bf16_t* WkF = WqF + 16384;
    bf16_t* WvF = WkF + 16384;
    bf16_t* WoF = WvF + 16384;

    pack_w<<<dim3(NH), 256, 0, stream>>>(Wq, Wk, Wv, Wo, WqF, WkF, WvF, WoF);
    fused_pipe3<<<dim3(512), 256, 0, stream>>>(Xq, Xkv, Mask, Bias,
                                               WqF, WkF, WvF, WoF, Bo, Out);
}

// Round 10
// 133.761 us; speedup vs baseline: 1.2525x; 1.0423x over previous
//
#include <hip/hip_runtime.h>

typedef __bf16 bf16_t;
typedef __bf16 bf16x4_t __attribute__((ext_vector_type(4)));
typedef __bf16 bf16x8 __attribute__((ext_vector_type(8)));
typedef float f32x4 __attribute__((ext_vector_type(4)));

#define NH 8
#define DH 32
#define QL 256
#define KL 256
#define CIN 64
#define HD 256  // NH*DH

__device__ __forceinline__ bf16_t f2bf(float x) { return (bf16_t)x; }

__device__ __forceinline__ f32x4 mfma16(bf16x8 a, bf16x8 b, f32x4 c) {
    return __builtin_amdgcn_mfma_f32_16x16x32_bf16(a, b, c, 0, 0, 0);
}

// raw v_exp_f32: D = 2^S0
__device__ __forceinline__ float exp2_raw(float x) {
    float r;
    asm("v_exp_f32 %0, %1" : "=v"(r) : "v"(x));
    return r;
}

// ---------------------------------------------------------------------------
// pack_w: one-time repack of Wq/Wk/Wv/Wo into fragment-native bf16 layout.
// Frag elem j at lane(quad,l16):
//   WqF/WkF/WvF: W[ks*32+quad*8+j][h*32 + nt*16 + l16]          (B-op, proj)
//   WoF (delta-packed): Wo[h*32 + (j>>2)*16 + quad*4 + (j&3)][nt*16+l16]
//     -- outproj k-sum relabeled so the O A-frag is lane-local (no bounce).
__launch_bounds__(256)
__global__ void pack_w(const float* __restrict__ Wq, const float* __restrict__ Wk,
                       const float* __restrict__ Wv, const float* __restrict__ Wo,
                       bf16_t* __restrict__ WqF, bf16_t* __restrict__ WkF,
                       bf16_t* __restrict__ WvF, bf16_t* __restrict__ WoF) {
    const int h = blockIdx.x;
    const int tid = threadIdx.x, lane = tid & 63, w = tid >> 6;
    const int quad = lane >> 4, l16 = lane & 15;
    if (w < 3) {
        const float* __restrict__ W = (w == 0) ? Wq : (w == 1 ? Wk : Wv);
        bf16_t* __restrict__ F = (w == 0) ? WqF : (w == 1 ? WkF : WvF);
#pragma unroll
        for (int nt = 0; nt < 2; ++nt)
#pragma unroll
            for (int ks = 0; ks < 2; ++ks) {
                bf16x8 f;
#pragma unroll
                for (int j = 0; j < 8; ++j)
                    f[j] = f2bf(W[(ks * 32 + quad * 8 + j) * HD + h * DH + nt * 16 + l16]);
                *(bf16x8*)&F[(size_t)((h * 4 + nt * 2 + ks) * 512) + lane * 8] = f;
            }
    } else {
#pragma unroll
        for (int nt = 0; nt < 4; ++nt) {
            bf16x8 f;
#pragma unroll
            for (int j = 0; j < 8; ++j)
                f[j] = f2bf(Wo[(h * DH + (j >> 2) * 16 + quad * 4 + (j & 3)) * CIN +
                               nt * 16 + l16]);
            *(bf16x8*)&WoF[(size_t)((h * 4 + nt) * 512) + lane * 8] = f;
        }
    }
}

// ---------------------------------------------------------------------------
// fused_pipe4: r9's LDS-free PV/outproj with its two latency holes plugged
// (r9 post-mortem: LESS issue but MORE time -> exposed latency):
//  (a) va software-pipelined 1 chunk ahead; va(0) prefetched BEFORE softmax
//      (sVT[p] valid from the phase barrier; only pf needs softmax) -- r9's
//      per-chunk ds_read->use lgkm stall (~120cy x8) gone.
//  (b) bias(h+1) loads interleaved into the PV loop right after chunk c's
//      pf is built (sv[2c],[2c+1] dead there): load-to-use = rest of PV +
//      outproj, zero extra registers -- r9 loaded after PV with only 4
//      MFMAs of cover.
// Everything else r9/r5-verbatim.
__launch_bounds__(256, 2)
__global__ void fused_pipe4(const float* __restrict__ Xq, const float* __restrict__ Xkv,
                            const float* __restrict__ Mask, const float* __restrict__ Bias,
                            const bf16_t* __restrict__ WqF, const bf16_t* __restrict__ WkF,
                            const bf16_t* __restrict__ WvF, const bf16_t* __restrict__ WoF,
                            const float* __restrict__ Bo, float* __restrict__ Out) {
    const int b = blockIdx.x;
    const int s = b & 127, qq = b >> 7;   // s fastest: same-s blocks share an XCD
    const int tid = threadIdx.x, lane = tid & 63, w = tid >> 6;
    const int quad = lane >> 4, l16 = lane & 15;
    const int tg = qq * 4 + w;            // this wave's global q-tile (16 rows)
    const f32x4 vzero = {0.f, 0.f, 0.f, 0.f};
    constexpr float L2E = 1.4426950408889634f;

    __shared__ __attribute__((aligned(16))) bf16_t sK[2][KL * 32];   // 32 KB dbuf, swz
    __shared__ __attribute__((aligned(16))) bf16_t sVT[2][DH][264];  // 33 KB dbuf
    __shared__ __attribute__((aligned(16))) bf16_t sPT[4][16][72];   //  9 KB Q bounce
    __shared__ __attribute__((aligned(16))) float sMask[KL];         //  1 KB

    // mask pre-combined AND pre-scaled by log2e: (m-1)*1e9*L2E
    if (tid < 64) {
        const f32x4 m4 = *(const f32x4*)&Mask[s * KL + tid * 4];
        f32x4 mm;
#pragma unroll
        for (int j = 0; j < 4; ++j) mm[j] = (m4[j] - 1.0f) * (1.0e9f * L2E);
        *(f32x4*)&sMask[tid * 4] = mm;
    }

    // ---- X fragments, register-resident for all 8 heads ----
    bf16x8 xk[4][2];  // Xkv A-frags: wave owns kv-tiles {4w..4w+3}
#pragma unroll
    for (int t = 0; t < 4; ++t) {
        const int row = (w * 4 + t) * 16 + l16;
        const float* src = &Xkv[(size_t)(s * QL + row) * CIN];
#pragma unroll
        for (int ks = 0; ks < 2; ++ks) {
            const f32x4 lo = *(const f32x4*)&src[ks * 32 + quad * 8];
            const f32x4 hi = *(const f32x4*)&src[ks * 32 + quad * 8 + 4];
            bf16x8 f;
#pragma unroll
            for (int j = 0; j < 4; ++j) { f[j] = f2bf(lo[j]); f[4 + j] = f2bf(hi[j]); }
            xk[t][ks] = f;
        }
    }
    bf16x8 xq[2];  // Xq A-frags, pre-scaled by (1/sqrt(32))*log2(e)
    {
        const int row = tg * 16 + l16;
        const float* src = &Xq[(size_t)(s * QL + row) * CIN];
        const float qs = 0.17677669529663687f * L2E;
#pragma unroll
        for (int ks = 0; ks < 2; ++ks) {
            const f32x4 lo = *(const f32x4*)&src[ks * 32 + quad * 8];
            const f32x4 hi = *(const f32x4*)&src[ks * 32 + quad * 8 + 4];
            bf16x8 f;
#pragma unroll
            for (int j = 0; j < 4; ++j) {
                f[j] = f2bf(lo[j] * qs);
                f[4 + j] = f2bf(hi[j] * qs);
            }
            xq[ks] = f;
        }
    }

    // K/V projection of head h into LDS buffer buf (r5-verbatim indexing)
    auto projKV = [&](int h, int buf) {
        bf16x8 bk[2][2], bv[2][2];
#pragma unroll
        for (int nt = 0; nt < 2; ++nt)
#pragma unroll
            for (int ks = 0; ks < 2; ++ks) {
                bk[nt][ks] = *(const bf16x8*)&WkF[(size_t)((h * 4 + nt * 2 + ks) * 512) + lane * 8];
                bv[nt][ks] = *(const bf16x8*)&WvF[(size_t)((h * 4 + nt * 2 + ks) * 512) + lane * 8];
            }
#pragma unroll
        for (int t = 0; t < 4; ++t) {
            const int r0 = (w * 4 + t) * 16 + quad * 4;
#pragma unroll
            for (int nt = 0; nt < 2; ++nt) {
                f32x4 c = mfma16(xk[t][0], bk[nt][0], vzero);
                c = mfma16(xk[t][1], bk[nt][1], c);
                const int chS = ((nt * 2 + (l16 >> 3)) ^ quad) << 3;
#pragma unroll
                for (int r = 0; r < 4; ++r)
                    sK[buf][(r0 + r) * 32 + chS + (l16 & 7)] = f2bf(c[r]);
            }
        }
#pragma unroll
        for (int t = 0; t < 4; ++t) {
            const int c0 = (w * 4 + t) * 16 + quad * 4;
#pragma unroll
            for (int nt = 0; nt < 2; ++nt) {
                f32x4 c = mfma16(xk[t][0], bv[nt][0], vzero);
                c = mfma16(xk[t][1], bv[nt][1], c);
                bf16x4_t p4;
#pragma unroll
                for (int r = 0; r < 4; ++r) p4[r] = f2bf(c[r]);
                *(bf16x4_t*)&sVT[buf][nt * 16 + l16][c0] = p4;
            }
        }
    };
    // Q projection (per-wave sPT bounce, same-wave DS order; r5-verbatim)
    auto projQ = [&](int h) -> bf16x8 {
        bf16x8 bq[2][2];
#pragma unroll
        for (int nt = 0; nt < 2; ++nt)
#pragma unroll
            for (int ks = 0; ks < 2; ++ks)
                bq[nt][ks] = *(const bf16x8*)&WqF[(size_t)((h * 4 + nt * 2 + ks) * 512) + lane * 8];
#pragma unroll
        for (int nt = 0; nt < 2; ++nt) {
            f32x4 c = mfma16(xq[0], bq[nt][0], vzero);
            c = mfma16(xq[1], bq[nt][1], c);
#pragma unroll
            for (int r = 0; r < 4; ++r) sPT[w][quad * 4 + r][nt * 16 + l16] = f2bf(c[r]);
        }
        return *(const bf16x8*)&sPT[w][l16][quad * 8];
    };

    // va pair for PV chunk c (sigma layout; from the proven sVT tiles)
    auto loadVA = [&](int p, int c, bf16x8& v0, bf16x8& v1) {
        const bf16x4_t a00 = *(const bf16x4_t*)&sVT[p][l16][c * 32 + quad * 4];
        const bf16x4_t a01 = *(const bf16x4_t*)&sVT[p][l16][c * 32 + 16 + quad * 4];
        const bf16x4_t a10 = *(const bf16x4_t*)&sVT[p][16 + l16][c * 32 + quad * 4];
        const bf16x4_t a11 = *(const bf16x4_t*)&sVT[p][16 + l16][c * 32 + 16 + quad * 4];
#pragma unroll
        for (int j = 0; j < 4; ++j) {
            v0[j] = a00[j];
            v0[4 + j] = a01[j];
            v1[j] = a10[j];
            v1[4 + j] = a11[j];
        }
    };

    f32x4 acc[4];  // output accumulator: 16 q-rows x 64 out-cols
#pragma unroll
    for (int nt = 0; nt < 4; ++nt) acc[nt] = vzero;

    // ---- prologue: bias(0) in flight, K/V(0) -> buf0, qfr(0) ready ----
    f32x4 sv[16];
    {
        const float* bb = &Bias[(size_t)(tg * 16 + l16) * KL];
#pragma unroll
        for (int ct = 0; ct < 16; ++ct) sv[ct] = *(const f32x4*)&bb[ct * 16 + quad * 4];
    }
    projKV(0, 0);
    bf16x8 qfr = projQ(0);
    __syncthreads();  // buf0 + sMask visible
#pragma unroll
    for (int ct = 0; ct < 16; ++ct) {
        const f32x4 m4 = *(const f32x4*)&sMask[ct * 16 + quad * 4];
#pragma unroll
        for (int r = 0; r < 4; ++r) sv[ct][r] = sv[ct][r] * L2E + m4[r];
    }

#pragma unroll 1
    for (int h = 0; h < NH; ++h) {
        const int p = h & 1;
        const int hn = (h + 1) & 7;  // branchless bias prefetch head (h=7 -> dummy)
        const float* bbn = &Bias[(size_t)(hn * QL + tg * 16 + l16) * KL];

        // ---- QK immediately: qfr + sv(=(bias+mask)*L2E) ready ----
#pragma unroll
        for (int ct = 0; ct < 16; ++ct) {
            const int row = ct * 16 + l16;
            const int chS = (quad ^ ((l16 >> 2) & 3)) << 3;
            const bf16x8 ak = *(const bf16x8*)&sK[p][row * 32 + chS];
            sv[ct] = mfma16(ak, qfr, sv[ct]);  // S' = S*log2e, bias+mask included
        }

        // ---- proj(h+1) into buf 1-p: independent MFMA filler ----
        if (h + 1 < NH) projKV(h + 1, p ^ 1);

        // ---- Wo frags (delta-packed; global, L2-hot; used at phase end) ----
        bf16x8 bwo[4];
#pragma unroll
        for (int nt = 0; nt < 4; ++nt)
            bwo[nt] = *(const bf16x8*)&WoF[(size_t)((h * 4 + nt) * 512) + lane * 8];

        // ---- va(0) prefetch: sVT[p] valid since the phase barrier ----
        bf16x8 vc0, vc1;
        loadVA(p, 0, vc0, vc1);

        // ---- softmax in exp2 domain (tree-reduced max; raw v_exp_f32) ----
        f32x4 vmx = sv[0];
#pragma unroll
        for (int ct = 1; ct < 16; ++ct)
#pragma unroll
            for (int r = 0; r < 4; ++r) vmx[r] = fmaxf(vmx[r], sv[ct][r]);
        float mx = fmaxf(fmaxf(vmx[0], vmx[1]), fmaxf(vmx[2], vmx[3]));
        mx = fmaxf(mx, __shfl_xor(mx, 16, 64));
        mx = fmaxf(mx, __shfl_xor(mx, 32, 64));
        f32x4 vsum = vzero;
#pragma unroll
        for (int ct = 0; ct < 16; ++ct)
#pragma unroll
            for (int r = 0; r < 4; ++r) {
                const float e = exp2_raw(sv[ct][r] - mx);
                sv[ct][r] = e;
                vsum[r] += e;
            }
        float sum = (vsum[0] + vsum[1]) + (vsum[2] + vsum[3]);
        sum += __shfl_xor(sum, 16, 64);
        sum += __shfl_xor(sum, 32, 64);
        const float rs = 1.0f / sum;  // consumed only after PV -> hides under it

        // ---- swapped PV (LDS-free P), va pipelined, bias loads interleaved ----
        // sigma(c,k)=32c+16*((k>>2)&1)+4*quad+(k&3):
        //   pf[j] = sv[2c+(j>>2)][j&3] (lane-local); va from proven sVT tiles.
        f32x4 ot0 = vzero, ot1 = vzero;
#pragma unroll
        for (int c = 0; c < 8; ++c) {
            bf16x8 vn0, vn1;
            if (c < 7) loadVA(p, c + 1, vn0, vn1);
            bf16x8 pf;
#pragma unroll
            for (int j = 0; j < 4; ++j) {
                pf[j] = f2bf(sv[2 * c][j]);
                pf[4 + j] = f2bf(sv[2 * c + 1][j]);
            }
            // sv[2c],[2c+1] dead now -> refill with bias(h+1): max load-to-use
            sv[2 * c] = *(const f32x4*)&bbn[(2 * c) * 16 + quad * 4];
            sv[2 * c + 1] = *(const f32x4*)&bbn[(2 * c + 1) * 16 + quad * 4];
            ot0 = mfma16(vc0, pf, ot0);  // O^T[d=quad*4+r][q=l16], d-tile 0
            ot1 = mfma16(vc1, pf, ot1);  // d-tile 1
            vc0 = vn0;
            vc1 = vn1;
        }

        // ---- outproj, LDS-free O: af[j] = ot[j>>2][j&3]*rs (delta-packed Wo) ----
        {
            bf16x8 af;
#pragma unroll
            for (int r = 0; r < 4; ++r) {
                af[r] = f2bf(ot0[r] * rs);
                af[4 + r] = f2bf(ot1[r] * rs);
            }
#pragma unroll
            for (int nt = 0; nt < 4; ++nt) acc[nt] = mfma16(af, bwo[nt], acc[nt]);
        }

        // ---- tail: Q(h+1); fold mask into the already-resident bias ----
        if (h + 1 < NH) {
            qfr = projQ(h + 1);
#pragma unroll
            for (int ct = 0; ct < 16; ++ct) {
                const f32x4 m4 = *(const f32x4*)&sMask[ct * 16 + quad * 4];
#pragma unroll
                for (int r = 0; r < 4; ++r) sv[ct][r] = sv[ct][r] * L2E + m4[r];
            }
        }

        __syncthreads();  // single barrier/head: buf 1-p ready, buf p free
    }

    // -------------------- epilogue: direct store --------------------
    const int orow = s * QL + tg * 16 + quad * 4;
#pragma unroll
    for (int nt = 0; nt < 4; ++nt) {
        const float bo = Bo[nt * 16 + l16];
#pragma unroll
        for (int r = 0; r < 4; ++r)
            Out[(size_t)(orow + r) * CIN + nt * 16 + l16] = acc[nt][r] + bo;
    }
}

extern "C" void kernel_launch(void* const* d_in, const int* in_sizes, int n_in,
                              void* d_out, int out_size, void* d_ws, size_t ws_size,
                              hipStream_t stream) {
    const float* Xq   = (const float*)d_in[0];
    const float* Xkv  = (const float*)d_in[1];
    const float* Mask = (const float*)d_in[2];
    const float* Bias = (const float*)d_in[3];
    const float* Wq   = (const float*)d_in[4];
    const float* Wk   = (const float*)d_in[5];
    const float* Wv   = (const float*)d_in[6];
    const float* Wo   = (const float*)d_in[7];
    const float* Bo   = (const float*)d_in[8];
    float* Out = (float*)d_out;

    // 128 KB of fragment-native weights at the head of ws
    bf16_t* WqF = (bf16_t*)d_ws;
    bf16_t* WkF = WqF + 16384;
    bf16_t* WvF = WkF + 16384;
    bf16_t* WoF = WvF + 16384;

    pack_w<<<dim3(NH), 256, 0, stream>>>(Wq, Wk, Wv, Wo, WqF, WkF, WvF, WoF);
    fused_pipe4<<<dim3(512), 256, 0, stream>>>(Xq, Xkv, Mask, Bias,
                                               WqF, WkF, WvF, WoF, Bo, Out);
}